// Round 15
// baseline (206.883 us; speedup 1.0000x reference)
//
#include <hip/hip_runtime.h>
#include <stdint.h>

// Titans-L2 chunked delta-rule forward — WY reformulation, MFMA everywhere.
//   1. cast x -> bf16; transpose+cast Wq/Wk/Wv into PACKED wqkvt [3072][1024];
//      Wo -> wot
//   2. ONE fused MFMA GEMM (256x256 tile, BK=64, 8 waves 2Mx4N, dbuf XOR-swz
//      LDS 128KB, COUNTED-vmcnt pipeline): [q|k|v] = x@[Wq|Wk|Wv]
//   3. wy_ab (per chunk): normalize k; S_neg = -a*tril(KK^T,-1) bf16 tiles;
//      PARALLEL Neumann-doubling diag inverses; right-looking substitution;
//      emits U,W bf16; A^T pre-swizzled bf16; B = W^T K bf16.
//   4. chunk_scan (MFMA): per (b,h), M_{c+1} = M_c A_c + B_c, M hi/lo bf16 LDS.
//   5. y_assemble: G = tril(QK^T,-1); Wt = W - a*(U M0^T); Y = Q M0^T + G Wt.
//   6. final MFMA GEMM y@Wo -> d_out (fp32)
// Dims: B=4 H=16 T=2048 C=1024 D=64 CS=128 nc=16 N=1024 tokens=8192

#define DEV __device__ __forceinline__

typedef __attribute__((ext_vector_type(4))) float f32x4;
typedef __attribute__((ext_vector_type(8))) __bf16 bf16x8;
typedef __attribute__((ext_vector_type(4))) __bf16 bf16x4;

typedef const __attribute__((address_space(1))) uint32_t* gas1_t;
typedef __attribute__((address_space(3))) uint32_t* las3_t;

DEV void gload_lds16(const void* g, void* l) {
  __builtin_amdgcn_global_load_lds((gas1_t)g, (las3_t)l, 16, 0, 0);
}

DEV float sgm(float x) { return 1.f / (1.f + __expf(-x)); }

template <int CTRL>
DEV float dpp_mov(float x) {
  return __builtin_bit_cast(
      float, __builtin_amdgcn_mov_dpp(__builtin_bit_cast(int, x), CTRL, 0xF, 0xF, true));
}
// cyclic rotate-reduce: sum over each 16-lane DPP row
DEV float row16_reduce(float x) {
  x += dpp_mov<0x121>(x);  // row_ror:1
  x += dpp_mov<0x122>(x);  // row_ror:2
  x += dpp_mov<0x124>(x);  // row_ror:4
  x += dpp_mov<0x128>(x);  // row_ror:8
  return x;
}

// ---- swizzled LDS helpers (row-major bf16 tiles; XOR bank swizzle) ----
DEV int swzb(int row, int col, int stride) {  // byte offset
  return ((row * stride + col) << 1) ^ ((row & 7) << 4);
}
DEV bf16x8 ldfrag(const __bf16* B, int row, int col, int stride) {
  return *(const bf16x8*)((const char*)B + swzb(row, col, stride));
}
DEV __bf16 ldsc(const __bf16* B, int row, int col, int stride) {
  return *(const __bf16*)((const char*)B + swzb(row, col, stride));
}
DEV void stb(__bf16* B, int row, int col, int stride, __bf16 v) {
  *(__bf16*)((char*)B + swzb(row, col, stride)) = v;
}
DEV void stb4(__bf16* B, int row, int c4, int stride, bf16x4 v) {
  *(bf16x4*)((char*)B + swzb(row, c4, stride)) = v;
}
// packed-lower tile offsets: row tr holds tiles 0..tr (+1 zero pad for even tr)
DEV int goffn(int tr) {
  int m = tr >> 1;
  return (tr & 1) ? (2 * m * m + 4 * m + 2) : (2 * m * m + 2 * m);
}
DEV int stile(int tr, int sc) { return ((tr * (tr + 1)) / 2 + sc) * 256; }

// ---------------- casts ----------------
__global__ __launch_bounds__(256) void cast_f32_bf16(const float* __restrict__ in,
                                                     __bf16* __restrict__ out) {
  int idx = blockIdx.x * 256 + threadIdx.x;
  float4 v = ((const float4*)in)[idx];
  bf16x4 o;
  o[0] = (__bf16)v.x; o[1] = (__bf16)v.y; o[2] = (__bf16)v.z; o[3] = (__bf16)v.w;
  ((bf16x4*)out)[idx] = o;
}

__global__ __launch_bounds__(256) void transpose_cast(const float* __restrict__ W,
                                                      __bf16* __restrict__ Wt) {
  __shared__ float tile[32][33];
  int tx = threadIdx.x & 31, ty = threadIdx.x >> 5;
  int n0 = blockIdx.x * 32, k0 = blockIdx.y * 32;
#pragma unroll
  for (int u = 0; u < 4; ++u)
    tile[ty + u * 8][tx] = W[(size_t)(k0 + ty + u * 8) * 1024 + n0 + tx];
  __syncthreads();
#pragma unroll
  for (int u = 0; u < 4; ++u)
    Wt[(size_t)(n0 + ty + u * 8) * 1024 + k0 + tx] = (__bf16)tile[tx][ty + u * 8];
}

// ---------------- GEMM: C[M=8192,N] = A[M,K=1024] * Bt[N,K]^T ----------------
// 256x256 tile, BK=64, 8 waves (2M x 4N, per-wave 128x64), double-buffered
// XOR-swizzled LDS (128 KB), COUNTED-vmcnt pipeline: raw s_barrier pair per
// K-tile, vmcnt(8) keeps next-tile loads in flight. XCD bijective remap.
// mode 0: fp32 C row-major [M,1024] (NBN=4).
// mode 1: bf16 scatter to 3 packed [B,H,T,D] buffers (NBN=12, col>>10 selects).
template <int CALLS>
DEV void stage_tile(const __bf16* __restrict__ G, __bf16* L, int t, int wid, int K) {
#pragma unroll
  for (int it = 0; it < CALLS; ++it) {
    int e = it * 512 + t;
    int row = e >> 3;
    int c0 = ((e & 7) ^ (row & 7)) << 3;
    gload_lds16(G + (size_t)row * K + c0, L + it * 4096 + wid * 512);
  }
}

__global__ __launch_bounds__(512, 2) void gemm_bt(const __bf16* __restrict__ A,
                                                  const __bf16* __restrict__ Bt,
                                                  float* __restrict__ Cf,
                                                  __bf16* __restrict__ Cb,
                                                  int mode, int NBN) {
  const int t = threadIdx.x;
  const int wid = t >> 6, lane = t & 63;
  const int fr = lane & 15, fkq = lane >> 4, fk = fkq * 8;
  const int wr = wid >> 2, wc = wid & 3;
  const int K = 1024;
  // XCD-aware bijective remap (gridDim.x % 8 == 0)
  int nwg = gridDim.x, lin = blockIdx.x;
  int q = nwg >> 3;
  int id2 = (lin & 7) * q + (lin >> 3);
  int bn = id2 % NBN, bm = id2 / NBN;
  __shared__ __bf16 lA[2][16384];  // [256][64] swz, 32KB each
  __shared__ __bf16 lB[2][16384];  // [256][64] swz, 32KB each
  const __bf16* Ab = A + (size_t)(bm * 256) * K;
  const __bf16* Bb = Bt + (size_t)(bn * 256) * K;
  f32x4 acc[8][4];
#pragma unroll
  for (int m = 0; m < 8; ++m)
#pragma unroll
    for (int nn = 0; nn < 4; ++nn) acc[m][nn] = 0.f;
  // prologue: stage tile 0 (8 vmem instructions per thread)
  stage_tile<4>(Ab, lA[0], t, wid, K);
  stage_tile<4>(Bb, lB[0], t, wid, K);
  for (int kt = 0; kt < 16; ++kt) {
    int cur = kt & 1;
    // barrier 1: all waves finished reading buf cur^1 (tile kt-1's compute)
    asm volatile("s_barrier" ::: "memory");
    if (kt < 15) {
      stage_tile<4>(Ab + (kt + 1) * 64, lA[cur ^ 1], t, wid, K);
      stage_tile<4>(Bb + (kt + 1) * 64, lB[cur ^ 1], t, wid, K);
      // wait tile kt's 8 loads (older); tile kt+1's 8 stay in flight
      asm volatile("s_waitcnt vmcnt(8)" ::: "memory");
    } else {
      asm volatile("s_waitcnt vmcnt(0)" ::: "memory");
    }
    // barrier 2: every wave's tile-kt loads have landed
    asm volatile("s_barrier" ::: "memory");
#pragma unroll
    for (int kk = 0; kk < 2; ++kk) {
      bf16x8 bg[4];
#pragma unroll
      for (int nn = 0; nn < 4; ++nn)
        bg[nn] = ldfrag(lB[cur], wc * 64 + nn * 16 + fr, kk * 32 + fk, 64);
#pragma unroll
      for (int m = 0; m < 8; ++m) {
        bf16x8 af = ldfrag(lA[cur], wr * 128 + m * 16 + fr, kk * 32 + fk, 64);
#pragma unroll
        for (int nn = 0; nn < 4; ++nn)
          acc[m][nn] =
              __builtin_amdgcn_mfma_f32_16x16x32_bf16(af, bg[nn], acc[m][nn], 0, 0, 0);
      }
    }
  }
#pragma unroll
  for (int m = 0; m < 8; ++m) {
#pragma unroll
    for (int nn = 0; nn < 4; ++nn) {
#pragma unroll
      for (int rg = 0; rg < 4; ++rg) {
        int row = bm * 256 + wr * 128 + m * 16 + fkq * 4 + rg;
        int col = bn * 256 + wc * 64 + nn * 16 + fr;
        float val = acc[m][nn][rg];
        if (mode == 0) {
          Cf[(size_t)row * 1024 + col] = val;
        } else {
          int buf = col >> 10, cc = col & 1023;
          int b = row >> 11, tk = row & 2047;
          int h = cc >> 6, d = cc & 63;
          Cb[(size_t)buf * 8388608 + (((size_t)b * 16 + h) * 2048 + tk) * 64 + d] =
              (__bf16)val;
        }
      }
    }
  }
}

// ---------------- fused WY solve + A/B (doubling inverse, register-resident) ----
// LDS 51.2 KB -> 3 blocks/CU. Wave w owns rows w*16..+15 of U,W in C/D regs.
__global__ __launch_bounds__(512, 6) void wy_ab(const __bf16* __restrict__ kb,
                                                const __bf16* __restrict__ vb,
                                                const float* __restrict__ ar,
                                                const float* __restrict__ br,
                                                __bf16* __restrict__ Ug,
                                                __bf16* __restrict__ Wgb,
                                                __bf16* __restrict__ ATg,
                                                __bf16* __restrict__ Bop) {
  int n = blockIdx.x, h = (n >> 4) & 15;
  float a = sgm(ar[h]) * 0.5f;
  float b = sgm(br[h]) * 0.5f;
  int t = threadIdx.x, wid = t >> 6, lane = t & 63;
  int fr = lane & 15, fkq = lane >> 4, fk = fkq * 8;
  __shared__ __attribute__((aligned(16))) char pool[51200];
  __bf16* Ks  = (__bf16*)pool;            // [128][64] swz; dead after U-init
  __bf16* MTu = (__bf16*)pool;            // [64][128] swz == U^T (overlays Ks)
  __bf16* MTw = (__bf16*)(pool + 16384);  // [64][128] swz == W^T
  __bf16* Sng = (__bf16*)(pool + 32768);  // 36 tiles; diag slots -> inv
  __bf16* KT  = (__bf16*)(pool + 32768);  // [64][128] swz (built late over Sng)
  const __bf16* kg = kb + (size_t)n * 8192;
  const __bf16* vg = vb + (size_t)n * 8192;
  bf16x8 zz;
#pragma unroll
  for (int e = 0; e < 8; ++e) zz[e] = (__bf16)0.f;
  f32x4 c0 = {0.f, 0.f, 0.f, 0.f};
  // stage: normalize k -> Ks (values kept in kreg for the late KT build)
  bf16x4 kreg[4];
#pragma unroll
  for (int it = 0; it < 4; ++it) {
    int u = it * 512 + t;
    int row = u >> 4, c4 = (u & 15) * 4;
    bf16x4 kh = ((const bf16x4*)kg)[u];
    float kf[4];
#pragma unroll
    for (int e = 0; e < 4; ++e) kf[e] = (float)kh[e];
    float ssq = kf[0] * kf[0] + kf[1] * kf[1] + kf[2] * kf[2] + kf[3] * kf[3];
    ssq = row16_reduce(ssq);
    float inv = 1.f / fmaxf(sqrtf(ssq), 1e-12f);
    bf16x4 kn;
#pragma unroll
    for (int e = 0; e < 4; ++e) kn[e] = (__bf16)(kf[e] * inv);
    kreg[it] = kn;
    stb4(Ks, row, c4, 64, kn);
  }
  __syncthreads();
  // S_neg = -(a * tril(KK^T)) packed-lower bf16 (diag tiles: col>=row -> 0)
  for (int p = wid; p < 36; p += 8) {
    int tr = 0, pp = p;
    while (pp > tr) { pp -= (tr + 1); ++tr; }
    int sc = pp;
    f32x4 acc = {0.f, 0.f, 0.f, 0.f};
#pragma unroll
    for (int ks = 0; ks < 2; ++ks)
      acc = __builtin_amdgcn_mfma_f32_16x16x32_bf16(
          ldfrag(Ks, tr * 16 + fr, ks * 32 + fk, 64),
          ldfrag(Ks, sc * 16 + fr, ks * 32 + fk, 64), acc, 0, 0, 0);
    __bf16* dst = Sng + stile(tr, sc);
#pragma unroll
    for (int rg = 0; rg < 4; ++rg) {
      int r = fkq * 4 + rg;
      float v = -a * acc[rg];
      if (tr == sc && fr >= r) v = 0.f;
      dst[r * 16 + fr] = (__bf16)v;
    }
  }
  // U,W init in C/D-layout registers (Ks reads complete before overlays)
  f32x4 U[4], W[4];
#pragma unroll
  for (int ct = 0; ct < 4; ++ct) {
#pragma unroll
    for (int rg = 0; rg < 4; ++rg) {
      int row = wid * 16 + fkq * 4 + rg, col = ct * 16 + fr;
      U[ct][rg] = (float)ldsc(Ks, row, col, 64);
      W[ct][rg] = b * (float)vg[row * 64 + col];
    }
  }
  __syncthreads();
  // ---- parallel diag inverse: inv(I-N) = (I+N)(I+N^2)(I+N^4)(I+N^8) ----
  {
    __bf16* scr  = ((__bf16*)pool) + wid * 2048;  // 4KB per wave
    __bf16* tNT  = scr;
    __bf16* tN2R = scr + 256;
    __bf16* tN2T = scr + 512;
    __bf16* tN4R = scr + 768;
    __bf16* tN4T = scr + 1024;
    __bf16* tN8T = scr + 1280;
    __bf16* tPR  = scr + 1536;
    __bf16* Nd = Sng + stile(wid, wid);
    float nv[4];
#pragma unroll
    for (int rg = 0; rg < 4; ++rg) {
      nv[rg] = (float)Nd[(fkq * 4 + rg) * 16 + fr];
      tNT[fr * 16 + fkq * 4 + rg] = (__bf16)nv[rg];
    }
    asm volatile("s_waitcnt lgkmcnt(0)" ::: "memory");
    bf16x8 af = (fk < 16) ? *(const bf16x8*)(Nd + fr * 16 + fk) : zz;
    bf16x8 bop = (fk < 16) ? *(const bf16x8*)(tNT + fr * 16 + fk) : zz;
    f32x4 X = __builtin_amdgcn_mfma_f32_16x16x32_bf16(af, bop, c0, 0, 0, 0);  // N^2
#pragma unroll
    for (int rg = 0; rg < 4; ++rg) {
      __bf16 v = (__bf16)X[rg];
      tN2R[(fkq * 4 + rg) * 16 + fr] = v;
      tN2T[fr * 16 + fkq * 4 + rg] = v;
    }
    asm volatile("s_waitcnt lgkmcnt(0)" ::: "memory");
    af = (fk < 16) ? *(const bf16x8*)(tN2R + fr * 16 + fk) : zz;
    bop = (fk < 16) ? *(const bf16x8*)(tN2T + fr * 16 + fk) : zz;
    X = __builtin_amdgcn_mfma_f32_16x16x32_bf16(af, bop, c0, 0, 0, 0);        // N^4
#pragma unroll
    for (int rg = 0; rg < 4; ++rg) {
      __bf16 v = (__bf16)X[rg];
      tN4R[(fkq * 4 + rg) * 16 + fr] = v;
      tN4T[fr * 16 + fkq * 4 + rg] = v;
    }
    asm volatile("s_waitcnt lgkmcnt(0)" ::: "memory");
    af = (fk < 16) ? *(const bf16x8*)(tN4R + fr * 16 + fk) : zz;
    bop = (fk < 16) ? *(const bf16x8*)(tN4T + fr * 16 + fk) : zz;
    X = __builtin_amdgcn_mfma_f32_16x16x32_bf16(af, bop, c0, 0, 0, 0);        // N^8
#pragma unroll
    for (int rg = 0; rg < 4; ++rg)
      tN8T[fr * 16 + fkq * 4 + rg] = (__bf16)X[rg];
    // P = I + N, then P *= (I+N^2), (I+N^4), (I+N^8) via C-init MFMA
    f32x4 P;
#pragma unroll
    for (int rg = 0; rg < 4; ++rg)
      P[rg] = ((fkq * 4 + rg) == fr ? 1.f : 0.f) + nv[rg];
#pragma unroll
    for (int d = 0; d < 3; ++d) {
      const __bf16* tB = (d == 0) ? tN2T : (d == 1) ? tN4T : tN8T;
#pragma unroll
      for (int rg = 0; rg < 4; ++rg)
        tPR[(fkq * 4 + rg) * 16 + fr] = (__bf16)P[rg];
      asm volatile("s_waitcnt lgkmcnt(0)" ::: "memory");
      af = (fk < 16) ? *(const bf16x8*)(tPR + fr * 16 + fk) : zz;
      bop = (fk < 16) ? *(const bf16x8*)(tB + fr * 16 + fk) : zz;
      P = __builtin_amdgcn_mfma_f32_16x16x32_bf16(af, bop, P, 0, 0, 0);
    }
#pragma unroll
    for (int rg = 0; rg < 4; ++rg)
      Nd[(fkq * 4 + rg) * 16 + fr] = (__bf16)P[rg];  // inv -> diag slot
  }
  __syncthreads();
  // right-looking substitution: stage bb = {wave bb: stage rhs, x = inv*rhs,
  // rewrite; barrier; waves>bb rank-16 MFMA update}
  for (int bb = 0; bb < 8; ++bb) {
    if (wid == bb) {
#pragma unroll
      for (int ct = 0; ct < 4; ++ct) {
        bf16x4 uu, ww;
#pragma unroll
        for (int rg = 0; rg < 4; ++rg) {
          uu[rg] = (__bf16)U[ct][rg];
          ww[rg] = (__bf16)W[ct][rg];
        }
        stb4(MTu, ct * 16 + fr, bb * 16 + fkq * 4, 128, uu);
        stb4(MTw, ct * 16 + fr, bb * 16 + fkq * 4, 128, ww);
      }
      asm volatile("s_waitcnt lgkmcnt(0)" ::: "memory");
      const __bf16* invT = Sng + stile(bb, bb);
      bf16x8 afv = (fk < 16) ? *(const bf16x8*)(invT + fr * 16 + fk) : zz;
#pragma unroll
      for (int ct = 0; ct < 4; ++ct) {
        bf16x8 bu = (fk < 16) ? ldfrag(MTu, ct * 16 + fr, bb * 16 + fk, 128) : zz;
        bf16x8 bw = (fk < 16) ? ldfrag(MTw, ct * 16 + fr, bb * 16 + fk, 128) : zz;
        U[ct] = __builtin_amdgcn_mfma_f32_16x16x32_bf16(afv, bu, c0, 0, 0, 0);
        W[ct] = __builtin_amdgcn_mfma_f32_16x16x32_bf16(afv, bw, c0, 0, 0, 0);
      }
#pragma unroll
      for (int ct = 0; ct < 4; ++ct) {
        bf16x4 uu, ww;
#pragma unroll
        for (int rg = 0; rg < 4; ++rg) {
          uu[rg] = (__bf16)U[ct][rg];
          ww[rg] = (__bf16)W[ct][rg];
        }
        stb4(MTu, ct * 16 + fr, bb * 16 + fkq * 4, 128, uu);
        stb4(MTw, ct * 16 + fr, bb * 16 + fkq * 4, 128, ww);
      }
    }
    __syncthreads();
    if (wid > bb) {
      bf16x8 af = zz;
      if (fk < 16) af = *(const bf16x8*)(Sng + stile(wid, bb) + fr * 16 + fk);
#pragma unroll
      for (int ct = 0; ct < 4; ++ct) {
        bf16x8 bu = zz, bw = zz;
        if (fk < 16) {
          bu = ldfrag(MTu, ct * 16 + fr, bb * 16 + fk, 128);
          bw = ldfrag(MTw, ct * 16 + fr, bb * 16 + fk, 128);
        }
        U[ct] = __builtin_amdgcn_mfma_f32_16x16x32_bf16(af, bu, U[ct], 0, 0, 0);
        W[ct] = __builtin_amdgcn_mfma_f32_16x16x32_bf16(af, bw, W[ct], 0, 0, 0);
      }
    }
  }
  // build KT over Sng (dead after last stage barrier) from register-held k
#pragma unroll
  for (int it = 0; it < 4; ++it) {
    int u = it * 512 + t;
    int row = u >> 4, c4 = (u & 15) * 4;
#pragma unroll
    for (int e = 0; e < 4; ++e) stb(KT, c4 + e, row, 128, kreg[it][e]);
  }
  // global bf16 write of U,W in [t][d] layout, straight from registers
  __bf16* ugo = Ug + (size_t)n * 8192;
  __bf16* wgo = Wgb + (size_t)n * 8192;
#pragma unroll
  for (int ct = 0; ct < 4; ++ct)
#pragma unroll
    for (int rg = 0; rg < 4; ++rg) {
      int row = wid * 16 + fkq * 4 + rg, col = ct * 16 + fr;
      ugo[row * 64 + col] = (__bf16)U[ct][rg];
      wgo[row * 64 + col] = (__bf16)W[ct][rg];
    }
  __syncthreads();
  // AT = I - a*(K^T U)  (pre-swizzled bf16), B = W^T K (bf16)
#pragma unroll
  for (int q = 0; q < 4; ++q) {
    int tile = wid + q * 8;  // 0-15 -> AT, 16-31 -> B
    int mat = tile >> 4;
    int ti = (tile >> 2) & 3, tj = tile & 3;
    f32x4 acc = {0.f, 0.f, 0.f, 0.f};
    if (mat == 0) {
#pragma unroll
      for (int ks = 0; ks < 4; ++ks)
        acc = __builtin_amdgcn_mfma_f32_16x16x32_bf16(
            ldfrag(KT, ti * 16 + fr, ks * 32 + fk, 128),
            ldfrag(MTu, tj * 16 + fr, ks * 32 + fk, 128), acc, 0, 0, 0);
      char* dst = (char*)(ATg + (size_t)n * 4096);
#pragma unroll
      for (int rg = 0; rg < 4; ++rg) {
        int i = ti * 16 + fkq * 4 + rg, j = tj * 16 + fr;
        float v = (i == j ? 1.f : 0.f) - a * acc[rg];
        *(__bf16*)(dst + swzb(i, j, 64)) = (__bf16)v;
      }
    } else {
#pragma unroll
      for (int ks = 0; ks < 4; ++ks)
        acc = __builtin_amdgcn_mfma_f32_16x16x32_bf16(
            ldfrag(MTw, ti * 16 + fr, ks * 32 + fk, 128),
            ldfrag(KT, tj * 16 + fr, ks * 32 + fk, 128), acc, 0, 0, 0);
      __bf16* dst = Bop + (size_t)n * 4096;
#pragma unroll
      for (int rg = 0; rg < 4; ++rg)
        dst[(ti * 16 + fkq * 4 + rg) * 64 + tj * 16 + fr] = (__bf16)acc[rg];
    }
  }
}

// ---------------- inter-chunk scan (MFMA) ----------------
__global__ __launch_bounds__(512) void chunk_scan(const __bf16* __restrict__ ATg,
                                                  const __bf16* __restrict__ Bop,
                                                  __bf16* __restrict__ Mst,
                                                  float* __restrict__ Mfinal) {
  int bh = blockIdx.x;
  int t = threadIdx.x, wid = t >> 6, lane = t & 63;
  int fr = lane & 15, fkq = lane >> 4, fk = fkq * 8;
  int ti = wid & 3, tj0 = (wid >> 2) << 1;
  __shared__ __bf16 Mh[4096];    // [64][64] swz
  __shared__ __bf16 Ml[4096];    // [64][64] swz
  __shared__ __bf16 At[2][4096]; // [64][64], pre-swizzled via linear gload_lds
  f32x4 acc[2];
  acc[0] = 0.f;
  acc[1] = 0.f;
  gload_lds16(ATg + (size_t)bh * 16 * 4096 + t * 8, At[0] + t * 8);
  for (int c = 0; c < 16; ++c) {
    int cur = c & 1;
    if (c < 15)
      gload_lds16(ATg + ((size_t)(bh * 16 + c + 1)) * 4096 + t * 8,
                  At[cur ^ 1] + t * 8);
    __bf16* mstc = Mst + ((size_t)(bh * 16 + c)) * 4096;
#pragma unroll
    for (int p = 0; p < 2; ++p) {
      int tj = tj0 + p;
#pragma unroll
      for (int rg = 0; rg < 4; ++rg) {
        int row = ti * 16 + fkq * 4 + rg, col = tj * 16 + fr;
        float v = acc[p][rg];
        __bf16 hi = (__bf16)v;
        mstc[row * 64 + col] = hi;
        stb(Mh, row, col, 64, hi);
        stb(Ml, row, col, 64, (__bf16)(v - (float)hi));
      }
    }
    __syncthreads();
    size_t bb = ((size_t)(bh * 16 + c)) * 4096;
#pragma unroll
    for (int p = 0; p < 2; ++p) {
      int tj = tj0 + p;
      f32x4 na;
#pragma unroll
      for (int rg = 0; rg < 4; ++rg)
        na[rg] = (float)Bop[bb + (ti * 16 + fkq * 4 + rg) * 64 + tj * 16 + fr];
#pragma unroll
      for (int ks = 0; ks < 2; ++ks) {
        bf16x8 bfrag = ldfrag(At[cur], tj * 16 + fr, ks * 32 + fk, 64);
        bf16x8 ah = ldfrag(Mh, ti * 16 + fr, ks * 32 + fk, 64);
        bf16x8 al = ldfrag(Ml, ti * 16 + fr, ks * 32 + fk, 64);
        na = __builtin_amdgcn_mfma_f32_16x16x32_bf16(ah, bfrag, na, 0, 0, 0);
        na = __builtin_amdgcn_mfma_f32_16x16x32_bf16(al, bfrag, na, 0, 0, 0);
      }
      acc[p] = na;
    }
    __syncthreads();
  }
#pragma unroll
  for (int p = 0; p < 2; ++p) {
    int tj = tj0 + p;
#pragma unroll
    for (int rg = 0; rg < 4; ++rg)
      Mfinal[(size_t)bh * 4096 + (ti * 16 + fkq * 4 + rg) * 64 + tj * 16 + fr] =
          acc[p][rg];
  }
}

// ---------------- Y assembly (plain bf16) ----------------
__global__ __launch_bounds__(512, 4) void y_assemble(const __bf16* __restrict__ qb,
                                                     const __bf16* __restrict__ kb,
                                                     const __bf16* __restrict__ Ug,
                                                     const __bf16* __restrict__ Wgb,
                                                     const __bf16* __restrict__ Mst,
                                                     const float* __restrict__ ar,
                                                     __bf16* __restrict__ ybf) {
  int n = blockIdx.x, h = (n >> 4) & 15, b = n >> 8, c = n & 15;
  float a = sgm(ar[h]) * 0.5f;
  int t = threadIdx.x, wid = t >> 6, lane = t & 63;
  int fr = lane & 15, fk = (lane >> 4) * 8;
  __shared__ __bf16 Qs[8192];    // [128][64] swz
  __shared__ __bf16 Rs[8192];    // [128][64] swz: K then U
  __shared__ __bf16 M0s[4096];   // [64][64] swz
  __shared__ __bf16 Gs[10240];   // 40 packed 16x16 tiles
  __shared__ __bf16 WtT[8192];   // [64][128] swz
  const __bf16* qg = qb + (size_t)n * 8192;
  const __bf16* kg = kb + (size_t)n * 8192;
  const __bf16* mg = Mst + (size_t)n * 4096;
#pragma unroll
  for (int it = 0; it < 4; ++it) {
    int u = it * 512 + t;
    int row = u >> 4, c4 = (u & 15) * 4;
    stb4(Qs, row, c4, 64, ((const bf16x4*)qg)[u]);
    bf16x4 kh = ((const bf16x4*)kg)[u];
    float kf[4];
#pragma unroll
    for (int e = 0; e < 4; ++e) kf[e] = (float)kh[e];
    float ssq = kf[0] * kf[0] + kf[1] * kf[1] + kf[2] * kf[2] + kf[3] * kf[3];
    ssq = row16_reduce(ssq);
    float inv = 1.f / fmaxf(sqrtf(ssq), 1e-12f);
    bf16x4 kn;
#pragma unroll
    for (int e = 0; e < 4; ++e) kn[e] = (__bf16)(kf[e] * inv);
    stb4(Rs, row, c4, 64, kn);
  }
#pragma unroll
  for (int it = 0; it < 2; ++it) {
    int u = it * 512 + t;
    int row = u >> 4, c4 = (u & 15) * 4;
    stb4(M0s, row, c4, 64, ((const bf16x4*)mg)[u]);
  }
#pragma unroll
  for (int pz = 0; pz < 2; ++pz) {
    int e = pz * 512 + t;
    int m = e >> 8, idx = e & 255;
    Gs[(2 * m * m + 4 * m + 1) * 256 + idx] = (__bf16)0.f;
  }
  __syncthreads();
  // P1: G = tril(Q K^T, -1), packed-lower bf16
  for (int p = wid; p < 36; p += 8) {
    int tr = 0, pp = p;
    while (pp > tr) { pp -= (tr + 1); ++tr; }
    int sc = pp;
    f32x4 acc = {0.f, 0.f, 0.f, 0.f};
#pragma unroll
    for (int ks = 0; ks < 2; ++ks)
      acc = __builtin_amdgcn_mfma_f32_16x16x32_bf16(
          ldfrag(Qs, tr * 16 + fr, ks * 32 + fk, 64),
          ldfrag(Rs, sc * 16 + fr, ks * 32 + fk, 64), acc, 0, 0, 0);
    int row0 = (lane >> 4) * 4, col = lane & 15;
    __bf16* gt = Gs + (goffn(tr) + sc) * 256;
#pragma unroll
    for (int rg = 0; rg < 4; ++rg) {
      int r = row0 + rg;
      float v = acc[rg];
      if (tr == sc && col >= r) v = 0.f;
      gt[r * 16 + col] = (__bf16)v;
    }
  }
  __syncthreads();
  // P2: restage Rs <- U
  const __bf16* ug = Ug + (size_t)n * 8192;
  const __bf16* wg = Wgb + (size_t)n * 8192;
#pragma unroll
  for (int it = 0; it < 4; ++it) {
    int u = it * 512 + t;
    int row = u >> 4, c4 = (u & 15) * 4;
    stb4(Rs, row, c4, 64, ((const bf16x4*)ug)[u]);
  }
  __syncthreads();
  // P3: WtT[i][s] = W[s][i] - a*(U M0^T)[s][i]
#pragma unroll
  for (int q = 0; q < 4; ++q) {
    int tile = wid + q * 8;
    int ti = tile >> 2, tj = tile & 3;
    f32x4 acc = {0.f, 0.f, 0.f, 0.f};
#pragma unroll
    for (int ks = 0; ks < 2; ++ks)
      acc = __builtin_amdgcn_mfma_f32_16x16x32_bf16(
          ldfrag(Rs, ti * 16 + fr, ks * 32 + fk, 64),
          ldfrag(M0s, tj * 16 + fr, ks * 32 + fk, 64), acc, 0, 0, 0);
    int row0 = (lane >> 4) * 4, col = lane & 15;
#pragma unroll
    for (int rg = 0; rg < 4; ++rg) {
      int s = ti * 16 + row0 + rg, i = tj * 16 + col;
      float wv = (float)wg[s * 64 + i];
      stb(WtT, i, s, 128, (__bf16)(wv - a * acc[rg]));
    }
  }
  __syncthreads();
  // P4: Y = Q M0^T + G Wt
  __bf16* yg = ybf + ((size_t)(b * 2048 + c * 128)) * 1024 + h * 64;
#pragma unroll
  for (int q = 0; q < 4; ++q) {
    int tile = wid + q * 8;
    int ti = tile >> 2, tj = tile & 3;
    f32x4 acc = {0.f, 0.f, 0.f, 0.f};
#pragma unroll
    for (int ks = 0; ks < 2; ++ks)
      acc = __builtin_amdgcn_mfma_f32_16x16x32_bf16(
          ldfrag(Qs, ti * 16 + fr, ks * 32 + fk, 64),
          ldfrag(M0s, tj * 16 + fr, ks * 32 + fk, 64), acc, 0, 0, 0);
    int goffv = goffn(ti);
    int np = (ti + 2) >> 1;
    for (int ks = 0; ks < np; ++ks) {
      int gtile = goffv + ks * 2 + (fk >> 4);
      bf16x8 af = *(const bf16x8*)(Gs + gtile * 256 + fr * 16 + (fk & 15));
      acc = __builtin_amdgcn_mfma_f32_16x16x32_bf16(
          af, ldfrag(WtT, tj * 16 + fr, ks * 32 + fk, 128), acc, 0, 0, 0);
    }
    int row0 = (lane >> 4) * 4, col = lane & 15;
#pragma unroll
    for (int rg = 0; rg < 4; ++rg) {
      int tt = ti * 16 + row0 + rg, d = tj * 16 + col;
      yg[(size_t)tt * 1024 + d] = (__bf16)acc[rg];
    }
  }
}

extern "C" void kernel_launch(void* const* d_in, const int* in_sizes, int n_in,
                              void* d_out, int out_size, void* d_ws, size_t ws_size,
                              hipStream_t stream) {
  const float* x  = (const float*)d_in[0];
  const float* Wq = (const float*)d_in[1];
  const float* Wk = (const float*)d_in[2];
  const float* Wv = (const float*)d_in[3];
  const float* Wo = (const float*)d_in[4];
  const float* ar = (const float*)d_in[5];
  const float* br = (const float*)d_in[6];

  char* ws = (char*)d_ws;
  __bf16* xb    = (__bf16*)ws;                     // 16.8 MB, reused as ybf
  __bf16* ybf   = xb;
  __bf16* wqkvt = (__bf16*)(ws + (17u << 20));     // 6 MB packed [3072][1024]
  __bf16* wot   = (__bf16*)(ws + (23u << 20));     // 2 MB
  __bf16* qb    = (__bf16*)(ws + (25u << 20));     // q,k,v contiguous, 8388608 elems each
  __bf16* kb    = qb + 8388608;
  __bf16* vb    = kb + 8388608;                    // ends at ~75.3 MB
  __bf16* Ugb   = (__bf16*)(ws + (76u << 20));
  __bf16* Wgb   = (__bf16*)(ws + (93u << 20));
  __bf16* ATg   = (__bf16*)(ws + (110u << 20));    // 8.4 MB (pre-swizzled)
  __bf16* Bop   = (__bf16*)(ws + (127u << 20));    // 8.4 MB bf16
  __bf16* Mst   = (__bf16*)(ws + (144u << 20));    // 8.4 MB

  float* yout = (float*)d_out;                     // [8192,1024] f32
  float* Mfin = yout + 8388608;

  cast_f32_bf16<<<8192, 256, 0, stream>>>(x, xb);
  dim3 tg(32, 32);
  transpose_cast<<<tg, 256, 0, stream>>>(Wq, wqkvt);
  transpose_cast<<<tg, 256, 0, stream>>>(Wk, wqkvt + (1u << 20));
  transpose_cast<<<tg, 256, 0, stream>>>(Wv, wqkvt + (2u << 20));
  transpose_cast<<<tg, 256, 0, stream>>>(Wo, wot);

  // fused QKV GEMM: M=8192, N=3072 -> grid 32*12 = 384 blocks of 256x256
  gemm_bt<<<384, 512, 0, stream>>>(xb, wqkvt, nullptr, qb, 1, 12);

  wy_ab<<<1024, 512, 0, stream>>>(kb, vb, ar, br, Ugb, Wgb, ATg, Bop);
  chunk_scan<<<64, 512, 0, stream>>>(ATg, Bop, Mst, Mfin);
  y_assemble<<<1024, 512, 0, stream>>>(qb, kb, Ugb, Wgb, Mst, ar, ybf);

  // final GEMM: M=8192, N=1024 -> grid 32*4 = 128 blocks of 256x256
  gemm_bt<<<128, 512, 0, stream>>>(ybf, wot, yout, nullptr, 0, 4);
}

// Round 16
// 185.045 us; speedup vs baseline: 1.1180x; 1.1180x over previous
//
#include <hip/hip_runtime.h>
#include <stdint.h>

// Titans-L2 chunked delta-rule forward — WY reformulation, MFMA everywhere.
//   1. cast x -> bf16; ONE fused transpose+cast of Wq/Wk/Wv/Wo into packed
//      [4096][1024] bf16 (wqkvt ++ wot contiguous)
//   2. ONE fused MFMA GEMM (128x128 tile, BK=32, 4 waves, RING-3 LDS 48KB ->
//      3 blocks/CU, counted-vmcnt pipeline): [q|k|v] = x@[Wq|Wk|Wv]
//   3. wy_ab (per chunk): normalize k; S_neg = -a*tril(KK^T,-1) bf16 tiles;
//      PARALLEL Neumann-doubling diag inverses; right-looking substitution;
//      emits U,W bf16; A^T pre-swizzled bf16; B = W^T K bf16.
//   4. chunk_scan (MFMA): per (b,h), M_{c+1} = M_c A_c + B_c, M hi/lo bf16 LDS.
//   5. y_assemble: G = tril(QK^T,-1); Wt = W - a*(U M0^T); Y = Q M0^T + G Wt.
//   6. final MFMA GEMM y@Wo -> d_out (fp32)
// Dims: B=4 H=16 T=2048 C=1024 D=64 CS=128 nc=16 N=1024 tokens=8192

#define DEV __device__ __forceinline__

typedef __attribute__((ext_vector_type(4))) float f32x4;
typedef __attribute__((ext_vector_type(8))) __bf16 bf16x8;
typedef __attribute__((ext_vector_type(4))) __bf16 bf16x4;

typedef const __attribute__((address_space(1))) uint32_t* gas1_t;
typedef __attribute__((address_space(3))) uint32_t* las3_t;

DEV void gload_lds16(const void* g, void* l) {
  __builtin_amdgcn_global_load_lds((gas1_t)g, (las3_t)l, 16, 0, 0);
}

DEV float sgm(float x) { return 1.f / (1.f + __expf(-x)); }

template <int CTRL>
DEV float dpp_mov(float x) {
  return __builtin_bit_cast(
      float, __builtin_amdgcn_mov_dpp(__builtin_bit_cast(int, x), CTRL, 0xF, 0xF, true));
}
// cyclic rotate-reduce: sum over each 16-lane DPP row
DEV float row16_reduce(float x) {
  x += dpp_mov<0x121>(x);  // row_ror:1
  x += dpp_mov<0x122>(x);  // row_ror:2
  x += dpp_mov<0x124>(x);  // row_ror:4
  x += dpp_mov<0x128>(x);  // row_ror:8
  return x;
}

// ---- swizzled LDS helpers (row-major bf16 tiles; XOR bank swizzle) ----
DEV int swzb(int row, int col, int stride) {  // byte offset
  return ((row * stride + col) << 1) ^ ((row & 7) << 4);
}
DEV bf16x8 ldfrag(const __bf16* B, int row, int col, int stride) {
  return *(const bf16x8*)((const char*)B + swzb(row, col, stride));
}
DEV __bf16 ldsc(const __bf16* B, int row, int col, int stride) {
  return *(const __bf16*)((const char*)B + swzb(row, col, stride));
}
DEV void stb(__bf16* B, int row, int col, int stride, __bf16 v) {
  *(__bf16*)((char*)B + swzb(row, col, stride)) = v;
}
DEV void stb4(__bf16* B, int row, int c4, int stride, bf16x4 v) {
  *(bf16x4*)((char*)B + swzb(row, c4, stride)) = v;
}
// packed-lower tile offsets: row tr holds tiles 0..tr (+1 zero pad for even tr)
DEV int goffn(int tr) {
  int m = tr >> 1;
  return (tr & 1) ? (2 * m * m + 4 * m + 2) : (2 * m * m + 2 * m);
}
DEV int stile(int tr, int sc) { return ((tr * (tr + 1)) / 2 + sc) * 256; }

// ---------------- casts ----------------
__global__ __launch_bounds__(256) void cast_f32_bf16(const float* __restrict__ in,
                                                     __bf16* __restrict__ out) {
  int idx = blockIdx.x * 256 + threadIdx.x;
  float4 v = ((const float4*)in)[idx];
  bf16x4 o;
  o[0] = (__bf16)v.x; o[1] = (__bf16)v.y; o[2] = (__bf16)v.z; o[3] = (__bf16)v.w;
  ((bf16x4*)out)[idx] = o;
}

// 4 weight matrices transposed+cast in one launch (z selects source)
__global__ __launch_bounds__(256) void transpose_cast4(const float* __restrict__ W0,
                                                       const float* __restrict__ W1,
                                                       const float* __restrict__ W2,
                                                       const float* __restrict__ W3,
                                                       __bf16* __restrict__ Wt) {
  const float* W = (blockIdx.z == 0) ? W0 : (blockIdx.z == 1) ? W1
                   : (blockIdx.z == 2) ? W2 : W3;
  __bf16* dst = Wt + ((size_t)blockIdx.z << 20);
  __shared__ float tile[32][33];
  int tx = threadIdx.x & 31, ty = threadIdx.x >> 5;
  int n0 = blockIdx.x * 32, k0 = blockIdx.y * 32;
#pragma unroll
  for (int u = 0; u < 4; ++u)
    tile[ty + u * 8][tx] = W[(size_t)(k0 + ty + u * 8) * 1024 + n0 + tx];
  __syncthreads();
#pragma unroll
  for (int u = 0; u < 4; ++u)
    dst[(size_t)(n0 + ty + u * 8) * 1024 + k0 + tx] = (__bf16)tile[tx][ty + u * 8];
}

// ---------------- GEMM: C[M=8192,N] = A[M,K=1024] * Bt[N,K]^T ----------------
// 128x128 tile, BK=32, 4 waves (2x2, per-wave 64x64), RING-3 granule-XOR
// swizzled LDS (48 KB -> 3 blocks/CU), counted-vmcnt: stage kt+2 during kt,
// vmcnt(8) keeps 2 tiles in flight across the raw barrier pair.
// mode 0: fp32 C row-major [M,1024] (NBN=8).
// mode 1: bf16 scatter to 3 packed [B,H,T,D] buffers (NBN=24, col>>10 selects).
// Tile [128][32] bf16 = 8KB = 512 granules of 16B; granule g of row r holds
// logical cols ((g^(r&3))*8..+8) -> pre-swizzled source, swizzled frag reads.
DEV void stage_tile32(const __bf16* __restrict__ G, __bf16* L, int t, int wid, int K) {
#pragma unroll
  for (int it = 0; it < 2; ++it) {
    int e = it * 256 + t;
    int row = e >> 2;
    int c0 = ((e & 3) ^ (row & 3)) << 3;
    gload_lds16(G + (size_t)row * K + c0, L + it * 2048 + wid * 512);
  }
}
DEV bf16x8 ldfrag32(const __bf16* L, int row, int fkq) {
  return *(const bf16x8*)(L + row * 32 + ((fkq ^ (row & 3)) << 3));
}

__global__ __launch_bounds__(256, 3) void gemm_bt(const __bf16* __restrict__ A,
                                                  const __bf16* __restrict__ Bt,
                                                  float* __restrict__ Cf,
                                                  __bf16* __restrict__ Cb,
                                                  int mode, int NBN) {
  const int t = threadIdx.x;
  const int wid = t >> 6, lane = t & 63;
  const int fr = lane & 15, fkq = lane >> 4;
  const int wr = wid >> 1, wc = wid & 1;
  const int K = 1024;
  // XCD-aware bijective remap (gridDim.x % 8 == 0)
  int nwg = gridDim.x, lin = blockIdx.x;
  int q = nwg >> 3;
  int id2 = (lin & 7) * q + (lin >> 3);
  int bn = id2 % NBN, bm = id2 / NBN;
  __shared__ __bf16 lA[3][4096];  // [128][32] swz, 8KB each
  __shared__ __bf16 lB[3][4096];
  const __bf16* Ab = A + (size_t)(bm * 128) * K;
  const __bf16* Bb = Bt + (size_t)(bn * 128) * K;
  f32x4 acc[4][4];
#pragma unroll
  for (int m = 0; m < 4; ++m)
#pragma unroll
    for (int nn = 0; nn < 4; ++nn) acc[m][nn] = 0.f;
  // prologue: stage tiles 0 and 1 (4 loads/thread each)
  stage_tile32(Ab, lA[0], t, wid, K);
  stage_tile32(Bb, lB[0], t, wid, K);
  stage_tile32(Ab + 32, lA[1], t, wid, K);
  stage_tile32(Bb + 32, lB[1], t, wid, K);
  int cur = 0;
  for (int kt = 0; kt < 32; ++kt) {
    // barrier 1: all waves finished reading tile kt-1 (slot (kt+2)%3)
    asm volatile("s_barrier" ::: "memory");
    if (kt + 2 < 32) {
      int nxt = cur >= 1 ? cur - 1 : cur + 2;  // (kt+2)%3
      stage_tile32(Ab + (kt + 2) * 32, lA[nxt], t, wid, K);
      stage_tile32(Bb + (kt + 2) * 32, lB[nxt], t, wid, K);
      // wait tile kt's 4 loads; kt+1 (4) + kt+2 (4) stay in flight
      asm volatile("s_waitcnt vmcnt(8)" ::: "memory");
    } else if (kt + 1 < 32) {
      asm volatile("s_waitcnt vmcnt(4)" ::: "memory");
    } else {
      asm volatile("s_waitcnt vmcnt(0)" ::: "memory");
    }
    // barrier 2: every wave's tile-kt loads have landed
    asm volatile("s_barrier" ::: "memory");
    bf16x8 af[4], bg[4];
#pragma unroll
    for (int m = 0; m < 4; ++m)
      af[m] = ldfrag32(lA[cur], wr * 64 + m * 16 + fr, fkq);
#pragma unroll
    for (int nn = 0; nn < 4; ++nn)
      bg[nn] = ldfrag32(lB[cur], wc * 64 + nn * 16 + fr, fkq);
#pragma unroll
    for (int m = 0; m < 4; ++m)
#pragma unroll
      for (int nn = 0; nn < 4; ++nn)
        acc[m][nn] =
            __builtin_amdgcn_mfma_f32_16x16x32_bf16(af[m], bg[nn], acc[m][nn], 0, 0, 0);
    cur = (cur < 2) ? cur + 1 : 0;
  }
#pragma unroll
  for (int m = 0; m < 4; ++m) {
#pragma unroll
    for (int nn = 0; nn < 4; ++nn) {
#pragma unroll
      for (int rg = 0; rg < 4; ++rg) {
        int row = bm * 128 + wr * 64 + m * 16 + fkq * 4 + rg;
        int col = bn * 128 + wc * 64 + nn * 16 + fr;
        float val = acc[m][nn][rg];
        if (mode == 0) {
          Cf[(size_t)row * 1024 + col] = val;
        } else {
          int buf = col >> 10, cc = col & 1023;
          int b = row >> 11, tk = row & 2047;
          int h = cc >> 6, d = cc & 63;
          Cb[(size_t)buf * 8388608 + (((size_t)b * 16 + h) * 2048 + tk) * 64 + d] =
              (__bf16)val;
        }
      }
    }
  }
}

// ---------------- fused WY solve + A/B (doubling inverse, register-resident) ----
// LDS 51.2 KB -> 3 blocks/CU. Wave w owns rows w*16..+15 of U,W in C/D regs.
__global__ __launch_bounds__(512, 6) void wy_ab(const __bf16* __restrict__ kb,
                                                const __bf16* __restrict__ vb,
                                                const float* __restrict__ ar,
                                                const float* __restrict__ br,
                                                __bf16* __restrict__ Ug,
                                                __bf16* __restrict__ Wgb,
                                                __bf16* __restrict__ ATg,
                                                __bf16* __restrict__ Bop) {
  int n = blockIdx.x, h = (n >> 4) & 15;
  float a = sgm(ar[h]) * 0.5f;
  float b = sgm(br[h]) * 0.5f;
  int t = threadIdx.x, wid = t >> 6, lane = t & 63;
  int fr = lane & 15, fkq = lane >> 4, fk = fkq * 8;
  __shared__ __attribute__((aligned(16))) char pool[51200];
  __bf16* Ks  = (__bf16*)pool;            // [128][64] swz; dead after U-init
  __bf16* MTu = (__bf16*)pool;            // [64][128] swz == U^T (overlays Ks)
  __bf16* MTw = (__bf16*)(pool + 16384);  // [64][128] swz == W^T
  __bf16* Sng = (__bf16*)(pool + 32768);  // 36 tiles; diag slots -> inv
  __bf16* KT  = (__bf16*)(pool + 32768);  // [64][128] swz (built late over Sng)
  const __bf16* kg = kb + (size_t)n * 8192;
  const __bf16* vg = vb + (size_t)n * 8192;
  bf16x8 zz;
#pragma unroll
  for (int e = 0; e < 8; ++e) zz[e] = (__bf16)0.f;
  f32x4 c0 = {0.f, 0.f, 0.f, 0.f};
  // stage: normalize k -> Ks (values kept in kreg for the late KT build)
  bf16x4 kreg[4];
#pragma unroll
  for (int it = 0; it < 4; ++it) {
    int u = it * 512 + t;
    int row = u >> 4, c4 = (u & 15) * 4;
    bf16x4 kh = ((const bf16x4*)kg)[u];
    float kf[4];
#pragma unroll
    for (int e = 0; e < 4; ++e) kf[e] = (float)kh[e];
    float ssq = kf[0] * kf[0] + kf[1] * kf[1] + kf[2] * kf[2] + kf[3] * kf[3];
    ssq = row16_reduce(ssq);
    float inv = 1.f / fmaxf(sqrtf(ssq), 1e-12f);
    bf16x4 kn;
#pragma unroll
    for (int e = 0; e < 4; ++e) kn[e] = (__bf16)(kf[e] * inv);
    kreg[it] = kn;
    stb4(Ks, row, c4, 64, kn);
  }
  __syncthreads();
  // S_neg = -(a * tril(KK^T)) packed-lower bf16 (diag tiles: col>=row -> 0)
  for (int p = wid; p < 36; p += 8) {
    int tr = 0, pp = p;
    while (pp > tr) { pp -= (tr + 1); ++tr; }
    int sc = pp;
    f32x4 acc = {0.f, 0.f, 0.f, 0.f};
#pragma unroll
    for (int ks = 0; ks < 2; ++ks)
      acc = __builtin_amdgcn_mfma_f32_16x16x32_bf16(
          ldfrag(Ks, tr * 16 + fr, ks * 32 + fk, 64),
          ldfrag(Ks, sc * 16 + fr, ks * 32 + fk, 64), acc, 0, 0, 0);
    __bf16* dst = Sng + stile(tr, sc);
#pragma unroll
    for (int rg = 0; rg < 4; ++rg) {
      int r = fkq * 4 + rg;
      float v = -a * acc[rg];
      if (tr == sc && fr >= r) v = 0.f;
      dst[r * 16 + fr] = (__bf16)v;
    }
  }
  // U,W init in C/D-layout registers (Ks reads complete before overlays)
  f32x4 U[4], W[4];
#pragma unroll
  for (int ct = 0; ct < 4; ++ct) {
#pragma unroll
    for (int rg = 0; rg < 4; ++rg) {
      int row = wid * 16 + fkq * 4 + rg, col = ct * 16 + fr;
      U[ct][rg] = (float)ldsc(Ks, row, col, 64);
      W[ct][rg] = b * (float)vg[row * 64 + col];
    }
  }
  __syncthreads();
  // ---- parallel diag inverse: inv(I-N) = (I+N)(I+N^2)(I+N^4)(I+N^8) ----
  {
    __bf16* scr  = ((__bf16*)pool) + wid * 2048;  // 4KB per wave
    __bf16* tNT  = scr;
    __bf16* tN2R = scr + 256;
    __bf16* tN2T = scr + 512;
    __bf16* tN4R = scr + 768;
    __bf16* tN4T = scr + 1024;
    __bf16* tN8T = scr + 1280;
    __bf16* tPR  = scr + 1536;
    __bf16* Nd = Sng + stile(wid, wid);
    float nv[4];
#pragma unroll
    for (int rg = 0; rg < 4; ++rg) {
      nv[rg] = (float)Nd[(fkq * 4 + rg) * 16 + fr];
      tNT[fr * 16 + fkq * 4 + rg] = (__bf16)nv[rg];
    }
    asm volatile("s_waitcnt lgkmcnt(0)" ::: "memory");
    bf16x8 af = (fk < 16) ? *(const bf16x8*)(Nd + fr * 16 + fk) : zz;
    bf16x8 bop = (fk < 16) ? *(const bf16x8*)(tNT + fr * 16 + fk) : zz;
    f32x4 X = __builtin_amdgcn_mfma_f32_16x16x32_bf16(af, bop, c0, 0, 0, 0);  // N^2
#pragma unroll
    for (int rg = 0; rg < 4; ++rg) {
      __bf16 v = (__bf16)X[rg];
      tN2R[(fkq * 4 + rg) * 16 + fr] = v;
      tN2T[fr * 16 + fkq * 4 + rg] = v;
    }
    asm volatile("s_waitcnt lgkmcnt(0)" ::: "memory");
    af = (fk < 16) ? *(const bf16x8*)(tN2R + fr * 16 + fk) : zz;
    bop = (fk < 16) ? *(const bf16x8*)(tN2T + fr * 16 + fk) : zz;
    X = __builtin_amdgcn_mfma_f32_16x16x32_bf16(af, bop, c0, 0, 0, 0);        // N^4
#pragma unroll
    for (int rg = 0; rg < 4; ++rg) {
      __bf16 v = (__bf16)X[rg];
      tN4R[(fkq * 4 + rg) * 16 + fr] = v;
      tN4T[fr * 16 + fkq * 4 + rg] = v;
    }
    asm volatile("s_waitcnt lgkmcnt(0)" ::: "memory");
    af = (fk < 16) ? *(const bf16x8*)(tN4R + fr * 16 + fk) : zz;
    bop = (fk < 16) ? *(const bf16x8*)(tN4T + fr * 16 + fk) : zz;
    X = __builtin_amdgcn_mfma_f32_16x16x32_bf16(af, bop, c0, 0, 0, 0);        // N^8
#pragma unroll
    for (int rg = 0; rg < 4; ++rg)
      tN8T[fr * 16 + fkq * 4 + rg] = (__bf16)X[rg];
    // P = I + N, then P *= (I+N^2), (I+N^4), (I+N^8) via C-init MFMA
    f32x4 P;
#pragma unroll
    for (int rg = 0; rg < 4; ++rg)
      P[rg] = ((fkq * 4 + rg) == fr ? 1.f : 0.f) + nv[rg];
#pragma unroll
    for (int d = 0; d < 3; ++d) {
      const __bf16* tB = (d == 0) ? tN2T : (d == 1) ? tN4T : tN8T;
#pragma unroll
      for (int rg = 0; rg < 4; ++rg)
        tPR[(fkq * 4 + rg) * 16 + fr] = (__bf16)P[rg];
      asm volatile("s_waitcnt lgkmcnt(0)" ::: "memory");
      af = (fk < 16) ? *(const bf16x8*)(tPR + fr * 16 + fk) : zz;
      bop = (fk < 16) ? *(const bf16x8*)(tB + fr * 16 + fk) : zz;
      P = __builtin_amdgcn_mfma_f32_16x16x32_bf16(af, bop, P, 0, 0, 0);
    }
#pragma unroll
    for (int rg = 0; rg < 4; ++rg)
      Nd[(fkq * 4 + rg) * 16 + fr] = (__bf16)P[rg];  // inv -> diag slot
  }
  __syncthreads();
  // right-looking substitution: stage bb = {wave bb: stage rhs, x = inv*rhs,
  // rewrite; barrier; waves>bb rank-16 MFMA update}
  for (int bb = 0; bb < 8; ++bb) {
    if (wid == bb) {
#pragma unroll
      for (int ct = 0; ct < 4; ++ct) {
        bf16x4 uu, ww;
#pragma unroll
        for (int rg = 0; rg < 4; ++rg) {
          uu[rg] = (__bf16)U[ct][rg];
          ww[rg] = (__bf16)W[ct][rg];
        }
        stb4(MTu, ct * 16 + fr, bb * 16 + fkq * 4, 128, uu);
        stb4(MTw, ct * 16 + fr, bb * 16 + fkq * 4, 128, ww);
      }
      asm volatile("s_waitcnt lgkmcnt(0)" ::: "memory");
      const __bf16* invT = Sng + stile(bb, bb);
      bf16x8 afv = (fk < 16) ? *(const bf16x8*)(invT + fr * 16 + fk) : zz;
#pragma unroll
      for (int ct = 0; ct < 4; ++ct) {
        bf16x8 bu = (fk < 16) ? ldfrag(MTu, ct * 16 + fr, bb * 16 + fk, 128) : zz;
        bf16x8 bw = (fk < 16) ? ldfrag(MTw, ct * 16 + fr, bb * 16 + fk, 128) : zz;
        U[ct] = __builtin_amdgcn_mfma_f32_16x16x32_bf16(afv, bu, c0, 0, 0, 0);
        W[ct] = __builtin_amdgcn_mfma_f32_16x16x32_bf16(afv, bw, c0, 0, 0, 0);
      }
#pragma unroll
      for (int ct = 0; ct < 4; ++ct) {
        bf16x4 uu, ww;
#pragma unroll
        for (int rg = 0; rg < 4; ++rg) {
          uu[rg] = (__bf16)U[ct][rg];
          ww[rg] = (__bf16)W[ct][rg];
        }
        stb4(MTu, ct * 16 + fr, bb * 16 + fkq * 4, 128, uu);
        stb4(MTw, ct * 16 + fr, bb * 16 + fkq * 4, 128, ww);
      }
    }
    __syncthreads();
    if (wid > bb) {
      bf16x8 af = zz;
      if (fk < 16) af = *(const bf16x8*)(Sng + stile(wid, bb) + fr * 16 + fk);
#pragma unroll
      for (int ct = 0; ct < 4; ++ct) {
        bf16x8 bu = zz, bw = zz;
        if (fk < 16) {
          bu = ldfrag(MTu, ct * 16 + fr, bb * 16 + fk, 128);
          bw = ldfrag(MTw, ct * 16 + fr, bb * 16 + fk, 128);
        }
        U[ct] = __builtin_amdgcn_mfma_f32_16x16x32_bf16(af, bu, U[ct], 0, 0, 0);
        W[ct] = __builtin_amdgcn_mfma_f32_16x16x32_bf16(af, bw, W[ct], 0, 0, 0);
      }
    }
  }
  // build KT over Sng (dead after last stage barrier) from register-held k
#pragma unroll
  for (int it = 0; it < 4; ++it) {
    int u = it * 512 + t;
    int row = u >> 4, c4 = (u & 15) * 4;
#pragma unroll
    for (int e = 0; e < 4; ++e) stb(KT, c4 + e, row, 128, kreg[it][e]);
  }
  // global bf16 write of U,W in [t][d] layout, straight from registers
  __bf16* ugo = Ug + (size_t)n * 8192;
  __bf16* wgo = Wgb + (size_t)n * 8192;
#pragma unroll
  for (int ct = 0; ct < 4; ++ct)
#pragma unroll
    for (int rg = 0; rg < 4; ++rg) {
      int row = wid * 16 + fkq * 4 + rg, col = ct * 16 + fr;
      ugo[row * 64 + col] = (__bf16)U[ct][rg];
      wgo[row * 64 + col] = (__bf16)W[ct][rg];
    }
  __syncthreads();
  // AT = I - a*(K^T U)  (pre-swizzled bf16), B = W^T K (bf16)
#pragma unroll
  for (int q = 0; q < 4; ++q) {
    int tile = wid + q * 8;  // 0-15 -> AT, 16-31 -> B
    int mat = tile >> 4;
    int ti = (tile >> 2) & 3, tj = tile & 3;
    f32x4 acc = {0.f, 0.f, 0.f, 0.f};
    if (mat == 0) {
#pragma unroll
      for (int ks = 0; ks < 4; ++ks)
        acc = __builtin_amdgcn_mfma_f32_16x16x32_bf16(
            ldfrag(KT, ti * 16 + fr, ks * 32 + fk, 128),
            ldfrag(MTu, tj * 16 + fr, ks * 32 + fk, 128), acc, 0, 0, 0);
      char* dst = (char*)(ATg + (size_t)n * 4096);
#pragma unroll
      for (int rg = 0; rg < 4; ++rg) {
        int i = ti * 16 + fkq * 4 + rg, j = tj * 16 + fr;
        float v = (i == j ? 1.f : 0.f) - a * acc[rg];
        *(__bf16*)(dst + swzb(i, j, 64)) = (__bf16)v;
      }
    } else {
#pragma unroll
      for (int ks = 0; ks < 4; ++ks)
        acc = __builtin_amdgcn_mfma_f32_16x16x32_bf16(
            ldfrag(MTw, ti * 16 + fr, ks * 32 + fk, 128),
            ldfrag(KT, tj * 16 + fr, ks * 32 + fk, 128), acc, 0, 0, 0);
      __bf16* dst = Bop + (size_t)n * 4096;
#pragma unroll
      for (int rg = 0; rg < 4; ++rg)
        dst[(ti * 16 + fkq * 4 + rg) * 64 + tj * 16 + fr] = (__bf16)acc[rg];
    }
  }
}

// ---------------- inter-chunk scan (MFMA) ----------------
__global__ __launch_bounds__(512) void chunk_scan(const __bf16* __restrict__ ATg,
                                                  const __bf16* __restrict__ Bop,
                                                  __bf16* __restrict__ Mst,
                                                  float* __restrict__ Mfinal) {
  int bh = blockIdx.x;
  int t = threadIdx.x, wid = t >> 6, lane = t & 63;
  int fr = lane & 15, fkq = lane >> 4, fk = fkq * 8;
  int ti = wid & 3, tj0 = (wid >> 2) << 1;
  __shared__ __bf16 Mh[4096];    // [64][64] swz
  __shared__ __bf16 Ml[4096];    // [64][64] swz
  __shared__ __bf16 At[2][4096]; // [64][64], pre-swizzled via linear gload_lds
  f32x4 acc[2];
  acc[0] = 0.f;
  acc[1] = 0.f;
  gload_lds16(ATg + (size_t)bh * 16 * 4096 + t * 8, At[0] + t * 8);
  for (int c = 0; c < 16; ++c) {
    int cur = c & 1;
    if (c < 15)
      gload_lds16(ATg + ((size_t)(bh * 16 + c + 1)) * 4096 + t * 8,
                  At[cur ^ 1] + t * 8);
    __bf16* mstc = Mst + ((size_t)(bh * 16 + c)) * 4096;
#pragma unroll
    for (int p = 0; p < 2; ++p) {
      int tj = tj0 + p;
#pragma unroll
      for (int rg = 0; rg < 4; ++rg) {
        int row = ti * 16 + fkq * 4 + rg, col = tj * 16 + fr;
        float v = acc[p][rg];
        __bf16 hi = (__bf16)v;
        mstc[row * 64 + col] = hi;
        stb(Mh, row, col, 64, hi);
        stb(Ml, row, col, 64, (__bf16)(v - (float)hi));
      }
    }
    __syncthreads();
    size_t bb = ((size_t)(bh * 16 + c)) * 4096;
#pragma unroll
    for (int p = 0; p < 2; ++p) {
      int tj = tj0 + p;
      f32x4 na;
#pragma unroll
      for (int rg = 0; rg < 4; ++rg)
        na[rg] = (float)Bop[bb + (ti * 16 + fkq * 4 + rg) * 64 + tj * 16 + fr];
#pragma unroll
      for (int ks = 0; ks < 2; ++ks) {
        bf16x8 bfrag = ldfrag(At[cur], tj * 16 + fr, ks * 32 + fk, 64);
        bf16x8 ah = ldfrag(Mh, ti * 16 + fr, ks * 32 + fk, 64);
        bf16x8 al = ldfrag(Ml, ti * 16 + fr, ks * 32 + fk, 64);
        na = __builtin_amdgcn_mfma_f32_16x16x32_bf16(ah, bfrag, na, 0, 0, 0);
        na = __builtin_amdgcn_mfma_f32_16x16x32_bf16(al, bfrag, na, 0, 0, 0);
      }
      acc[p] = na;
    }
    __syncthreads();
  }
#pragma unroll
  for (int p = 0; p < 2; ++p) {
    int tj = tj0 + p;
#pragma unroll
    for (int rg = 0; rg < 4; ++rg)
      Mfinal[(size_t)bh * 4096 + (ti * 16 + fkq * 4 + rg) * 64 + tj * 16 + fr] =
          acc[p][rg];
  }
}

// ---------------- Y assembly (plain bf16) ----------------
__global__ __launch_bounds__(512, 4) void y_assemble(const __bf16* __restrict__ qb,
                                                     const __bf16* __restrict__ kb,
                                                     const __bf16* __restrict__ Ug,
                                                     const __bf16* __restrict__ Wgb,
                                                     const __bf16* __restrict__ Mst,
                                                     const float* __restrict__ ar,
                                                     __bf16* __restrict__ ybf) {
  int n = blockIdx.x, h = (n >> 4) & 15, b = n >> 8, c = n & 15;
  float a = sgm(ar[h]) * 0.5f;
  int t = threadIdx.x, wid = t >> 6, lane = t & 63;
  int fr = lane & 15, fk = (lane >> 4) * 8;
  __shared__ __bf16 Qs[8192];    // [128][64] swz
  __shared__ __bf16 Rs[8192];    // [128][64] swz: K then U
  __shared__ __bf16 M0s[4096];   // [64][64] swz
  __shared__ __bf16 Gs[10240];   // 40 packed 16x16 tiles
  __shared__ __bf16 WtT[8192];   // [64][128] swz
  const __bf16* qg = qb + (size_t)n * 8192;
  const __bf16* kg = kb + (size_t)n * 8192;
  const __bf16* mg = Mst + (size_t)n * 4096;
#pragma unroll
  for (int it = 0; it < 4; ++it) {
    int u = it * 512 + t;
    int row = u >> 4, c4 = (u & 15) * 4;
    stb4(Qs, row, c4, 64, ((const bf16x4*)qg)[u]);
    bf16x4 kh = ((const bf16x4*)kg)[u];
    float kf[4];
#pragma unroll
    for (int e = 0; e < 4; ++e) kf[e] = (float)kh[e];
    float ssq = kf[0] * kf[0] + kf[1] * kf[1] + kf[2] * kf[2] + kf[3] * kf[3];
    ssq = row16_reduce(ssq);
    float inv = 1.f / fmaxf(sqrtf(ssq), 1e-12f);
    bf16x4 kn;
#pragma unroll
    for (int e = 0; e < 4; ++e) kn[e] = (__bf16)(kf[e] * inv);
    stb4(Rs, row, c4, 64, kn);
  }
#pragma unroll
  for (int it = 0; it < 2; ++it) {
    int u = it * 512 + t;
    int row = u >> 4, c4 = (u & 15) * 4;
    stb4(M0s, row, c4, 64, ((const bf16x4*)mg)[u]);
  }
#pragma unroll
  for (int pz = 0; pz < 2; ++pz) {
    int e = pz * 512 + t;
    int m = e >> 8, idx = e & 255;
    Gs[(2 * m * m + 4 * m + 1) * 256 + idx] = (__bf16)0.f;
  }
  __syncthreads();
  // P1: G = tril(Q K^T, -1), packed-lower bf16
  for (int p = wid; p < 36; p += 8) {
    int tr = 0, pp = p;
    while (pp > tr) { pp -= (tr + 1); ++tr; }
    int sc = pp;
    f32x4 acc = {0.f, 0.f, 0.f, 0.f};
#pragma unroll
    for (int ks = 0; ks < 2; ++ks)
      acc = __builtin_amdgcn_mfma_f32_16x16x32_bf16(
          ldfrag(Qs, tr * 16 + fr, ks * 32 + fk, 64),
          ldfrag(Rs, sc * 16 + fr, ks * 32 + fk, 64), acc, 0, 0, 0);
    int row0 = (lane >> 4) * 4, col = lane & 15;
    __bf16* gt = Gs + (goffn(tr) + sc) * 256;
#pragma unroll
    for (int rg = 0; rg < 4; ++rg) {
      int r = row0 + rg;
      float v = acc[rg];
      if (tr == sc && col >= r) v = 0.f;
      gt[r * 16 + col] = (__bf16)v;
    }
  }
  __syncthreads();
  // P2: restage Rs <- U
  const __bf16* ug = Ug + (size_t)n * 8192;
  const __bf16* wg = Wgb + (size_t)n * 8192;
#pragma unroll
  for (int it = 0; it < 4; ++it) {
    int u = it * 512 + t;
    int row = u >> 4, c4 = (u & 15) * 4;
    stb4(Rs, row, c4, 64, ((const bf16x4*)ug)[u]);
  }
  __syncthreads();
  // P3: WtT[i][s] = W[s][i] - a*(U M0^T)[s][i]
#pragma unroll
  for (int q = 0; q < 4; ++q) {
    int tile = wid + q * 8;
    int ti = tile >> 2, tj = tile & 3;
    f32x4 acc = {0.f, 0.f, 0.f, 0.f};
#pragma unroll
    for (int ks = 0; ks < 2; ++ks)
      acc = __builtin_amdgcn_mfma_f32_16x16x32_bf16(
          ldfrag(Rs, ti * 16 + fr, ks * 32 + fk, 64),
          ldfrag(M0s, tj * 16 + fr, ks * 32 + fk, 64), acc, 0, 0, 0);
    int row0 = (lane >> 4) * 4, col = lane & 15;
#pragma unroll
    for (int rg = 0; rg < 4; ++rg) {
      int s = ti * 16 + row0 + rg, i = tj * 16 + col;
      float wv = (float)wg[s * 64 + i];
      stb(WtT, i, s, 128, (__bf16)(wv - a * acc[rg]));
    }
  }
  __syncthreads();
  // P4: Y = Q M0^T + G Wt
  __bf16* yg = ybf + ((size_t)(b * 2048 + c * 128)) * 1024 + h * 64;
#pragma unroll
  for (int q = 0; q < 4; ++q) {
    int tile = wid + q * 8;
    int ti = tile >> 2, tj = tile & 3;
    f32x4 acc = {0.f, 0.f, 0.f, 0.f};
#pragma unroll
    for (int ks = 0; ks < 2; ++ks)
      acc = __builtin_amdgcn_mfma_f32_16x16x32_bf16(
          ldfrag(Qs, ti * 16 + fr, ks * 32 + fk, 64),
          ldfrag(M0s, tj * 16 + fr, ks * 32 + fk, 64), acc, 0, 0, 0);
    int goffv = goffn(ti);
    int np = (ti + 2) >> 1;
    for (int ks = 0; ks < np; ++ks) {
      int gtile = goffv + ks * 2 + (fk >> 4);
      bf16x8 af = *(const bf16x8*)(Gs + gtile * 256 + fr * 16 + (fk & 15));
      acc = __builtin_amdgcn_mfma_f32_16x16x32_bf16(
          af, ldfrag(WtT, tj * 16 + fr, ks * 32 + fk, 128), acc, 0, 0, 0);
    }
    int row0 = (lane >> 4) * 4, col = lane & 15;
#pragma unroll
    for (int rg = 0; rg < 4; ++rg) {
      int tt = ti * 16 + row0 + rg, d = tj * 16 + col;
      yg[(size_t)tt * 1024 + d] = (__bf16)acc[rg];
    }
  }
}

extern "C" void kernel_launch(void* const* d_in, const int* in_sizes, int n_in,
                              void* d_out, int out_size, void* d_ws, size_t ws_size,
                              hipStream_t stream) {
  const float* x  = (const float*)d_in[0];
  const float* Wq = (const float*)d_in[1];
  const float* Wk = (const float*)d_in[2];
  const float* Wv = (const float*)d_in[3];
  const float* Wo = (const float*)d_in[4];
  const float* ar = (const float*)d_in[5];
  const float* br = (const float*)d_in[6];

  char* ws = (char*)d_ws;
  __bf16* xb    = (__bf16*)ws;                     // 16.8 MB, reused as ybf
  __bf16* ybf   = xb;
  __bf16* wqkvt = (__bf16*)(ws + (17u << 20));     // 8 MB packed [4096][1024]
  __bf16* wot   = wqkvt + (3u << 20);              // last quarter = Wo^T
  __bf16* qb    = (__bf16*)(ws + (25u << 20));     // q,k,v contiguous
  __bf16* kb    = qb + 8388608;
  __bf16* vb    = kb + 8388608;
  __bf16* Ugb   = (__bf16*)(ws + (76u << 20));
  __bf16* Wgb   = (__bf16*)(ws + (93u << 20));
  __bf16* ATg   = (__bf16*)(ws + (110u << 20));    // 8.4 MB (pre-swizzled)
  __bf16* Bop   = (__bf16*)(ws + (127u << 20));    // 8.4 MB bf16
  __bf16* Mst   = (__bf16*)(ws + (144u << 20));    // 8.4 MB

  float* yout = (float*)d_out;                     // [8192,1024] f32
  float* Mfin = yout + 8388608;

  cast_f32_bf16<<<8192, 256, 0, stream>>>(x, xb);
  transpose_cast4<<<dim3(32, 32, 4), 256, 0, stream>>>(Wq, Wk, Wv, Wo, wqkvt);

  // fused QKV GEMM: M=8192, N=3072 -> grid 64*24 = 1536 blocks of 128x128
  gemm_bt<<<1536, 256, 0, stream>>>(xb, wqkvt, nullptr, qb, 1, 24);

  wy_ab<<<1024, 512, 0, stream>>>(kb, vb, ar, br, Ugb, Wgb, ATg, Bop);
  chunk_scan<<<64, 512, 0, stream>>>(ATg, Bop, Mst, Mfin);
  y_assemble<<<1024, 512, 0, stream>>>(qb, kb, Ugb, Wgb, Mst, ar, ybf);

  // final GEMM: M=8192, N=1024 -> grid 64*8 = 512 blocks of 128x128
  gemm_bt<<<512, 256, 0, stream>>>(ybf, wot, yout, nullptr, 0, 8);
}